// Round 1
// baseline (321.619 us; speedup 1.0000x reference)
//
#include <hip/hip_runtime.h>

#define N 8192
#define D 128
#define NC 512
#define CSZ 16

// ---------------- kernel 1: sq norms + minkey init ----------------
__global__ void k_sq_init(const float* __restrict__ x, float* __restrict__ sq,
                          unsigned long long* __restrict__ minkey) {
    int i = blockIdx.x * blockDim.x + threadIdx.x;
    if (i >= N) return;
    const float4* xr = (const float4*)(x + (size_t)i * D);
    float s = 0.f;
#pragma unroll
    for (int k = 0; k < D / 4; ++k) {
        float4 v = xr[k];
        s += v.x * v.x + v.y * v.y + v.z * v.z + v.w * v.w;
    }
    sq[i] = s;
    minkey[i] = ~0ULL;
}

// ---------------- kernel 2: hardest positive (within 16-elem cluster) -------
__global__ __launch_bounds__(256) void k_pos(const float* __restrict__ x,
                                             float* __restrict__ d_ap) {
    __shared__ __align__(16) float Xs[CSZ][D + 4];
    __shared__ float dist[CSZ][CSZ + 1];
    int c = blockIdx.x;
    int tid = threadIdx.x;
    // stage 16x128 floats = 512 float4, 2 per thread
#pragma unroll
    for (int it = 0; it < 2; ++it) {
        int idx = tid + it * 256;     // float4 index
        int r = idx >> 5, k4 = idx & 31;
        float4 v = *(const float4*)(x + (size_t)(c * CSZ + r) * D + k4 * 4);
        Xs[r][k4 * 4 + 0] = v.x;
        Xs[r][k4 * 4 + 1] = v.y;
        Xs[r][k4 * 4 + 2] = v.z;
        Xs[r][k4 * 4 + 3] = v.w;
    }
    __syncthreads();
    int r = tid >> 4, cc = tid & 15;
    float s = 0.f;
#pragma unroll 8
    for (int k = 0; k < D; ++k) {
        float d = Xs[r][k] - Xs[cc][k];
        s += d * d;
    }
    dist[r][cc] = sqrtf(s);
    __syncthreads();
    if (tid < CSZ) {
        float best = -1.f;
#pragma unroll
        for (int j = 0; j < CSZ; ++j) {
            float v = dist[tid][j];
            if (v > best) best = v;
        }
        d_ap[c * CSZ + tid] = best;  // exact: computed from direct diffs
    }
}

// ---------------- kernel 3: hardest negative (tiled distance "GEMM") --------
#define BM 64
#define BN 64

__global__ __launch_bounds__(256) void k_neg(const float* __restrict__ x,
                                             const float* __restrict__ sq,
                                             unsigned long long* __restrict__ minkey) {
    __shared__ __align__(16) float As[D][BM + 4];    // transposed A, full K
    __shared__ __align__(16) float Bs[64][BN + 4];   // transposed B, half K
    __shared__ unsigned long long red[BM][16];

    const int row0 = blockIdx.x * BM;
    const int colg = blockIdx.y;            // 0..7, each covers 1024 cols
    const int tid = threadIdx.x;
    const int tx = tid & 15, ty = tid >> 4;

    // stage A transposed: 64 rows x 128 k -> 2048 float4, 8/thread, coalesced
#pragma unroll
    for (int it = 0; it < 8; ++it) {
        int idx = tid + it * 256;
        int r = idx >> 5, k4 = idx & 31;
        float4 v = *(const float4*)(x + (size_t)(row0 + r) * D + k4 * 4);
        As[k4 * 4 + 0][r] = v.x;
        As[k4 * 4 + 1][r] = v.y;
        As[k4 * 4 + 2][r] = v.z;
        As[k4 * 4 + 3][r] = v.w;
    }

    float sqi[4];
#pragma unroll
    for (int ii = 0; ii < 4; ++ii) sqi[ii] = sq[row0 + ty * 4 + ii];

    unsigned long long best[4] = {~0ULL, ~0ULL, ~0ULL, ~0ULL};

    for (int ch = 0; ch < 16; ++ch) {
        const int c0 = colg * 1024 + ch * 64;
        float acc[4][4] = {};
#pragma unroll
        for (int kh = 0; kh < 2; ++kh) {
            __syncthreads();   // also covers As staging on first pass / Bs reuse
            // stage B half-K transposed: 64 cols x 64 k -> 1024 float4, 4/thread
#pragma unroll
            for (int it = 0; it < 4; ++it) {
                int idx = tid + it * 256;
                int cj = idx >> 4, k4 = idx & 15;
                float4 v = *(const float4*)(x + (size_t)(c0 + cj) * D + kh * 64 + k4 * 4);
                Bs[k4 * 4 + 0][cj] = v.x;
                Bs[k4 * 4 + 1][cj] = v.y;
                Bs[k4 * 4 + 2][cj] = v.z;
                Bs[k4 * 4 + 3][cj] = v.w;
            }
            __syncthreads();
#pragma unroll 16
            for (int k = 0; k < 64; ++k) {
                float4 a = *(const float4*)&As[kh * 64 + k][ty * 4];
                float4 b = *(const float4*)&Bs[k][tx * 4];
                acc[0][0] += a.x * b.x; acc[0][1] += a.x * b.y; acc[0][2] += a.x * b.z; acc[0][3] += a.x * b.w;
                acc[1][0] += a.y * b.x; acc[1][1] += a.y * b.y; acc[1][2] += a.y * b.z; acc[1][3] += a.y * b.w;
                acc[2][0] += a.z * b.x; acc[2][1] += a.z * b.y; acc[2][2] += a.z * b.z; acc[2][3] += a.z * b.w;
                acc[3][0] += a.w * b.x; acc[3][1] += a.w * b.y; acc[3][2] += a.w * b.z; acc[3][3] += a.w * b.w;
            }
        }
        // fold this 64x64 tile into per-row running min keys
#pragma unroll
        for (int ii = 0; ii < 4; ++ii) {
            const int gi = row0 + ty * 4 + ii;
#pragma unroll
            for (int jj = 0; jj < 4; ++jj) {
                const int gj = c0 + tx * 4 + jj;
                if ((gi >> 4) == (gj >> 4)) continue;  // same cluster -> excluded
                float d2 = sqi[ii] + sq[gj] - 2.f * acc[ii][jj];
                d2 = fmaxf(d2, 0.f);
                unsigned long long key =
                    ((unsigned long long)__float_as_uint(d2) << 32) | (unsigned int)gj;
                if (key < best[ii]) best[ii] = key;
            }
        }
    }

    __syncthreads();
#pragma unroll
    for (int ii = 0; ii < 4; ++ii) red[ty * 4 + ii][tx] = best[ii];
    __syncthreads();
    if (tid < BM) {
        unsigned long long m = red[tid][0];
#pragma unroll
        for (int t = 1; t < 16; ++t)
            if (red[tid][t] < m) m = red[tid][t];
        atomicMin(&minkey[row0 + tid], m);
    }
}

// ---------------- kernel 4: exact d_an + triplet loss ----------------
__global__ void k_final(const float* __restrict__ x,
                        const unsigned long long* __restrict__ minkey,
                        const float* __restrict__ d_ap, float* __restrict__ out) {
    int i = blockIdx.x * blockDim.x + threadIdx.x;
    if (i >= N) return;
    int j = (int)(minkey[i] & 0xFFFFFFFFULL);
    const float4* xi = (const float4*)(x + (size_t)i * D);
    const float4* xj = (const float4*)(x + (size_t)j * D);
    float s = 0.f;
#pragma unroll
    for (int k = 0; k < D / 4; ++k) {
        float4 a = xi[k], b = xj[k];
        float dx = a.x - b.x, dy = a.y - b.y, dz = a.z - b.z, dw = a.w - b.w;
        s += dx * dx + dy * dy + dz * dz + dw * dw;
    }
    float d_an = sqrtf(s);
    out[i] = fmaxf(d_ap[i] - d_an + 1.0f, 0.0f);
}

extern "C" void kernel_launch(void* const* d_in, const int* in_sizes, int n_in,
                              void* d_out, int out_size, void* d_ws, size_t ws_size,
                              hipStream_t stream) {
    const float* x = (const float*)d_in[0];
    float* out = (float*)d_out;

    char* ws = (char*)d_ws;
    float* sq = (float*)ws;                                   // 32 KB
    unsigned long long* minkey = (unsigned long long*)(ws + 32768);  // 64 KB
    float* d_ap = (float*)(ws + 98304);                       // 32 KB

    k_sq_init<<<N / 256, 256, 0, stream>>>(x, sq, minkey);
    k_pos<<<NC, 256, 0, stream>>>(x, d_ap);
    k_neg<<<dim3(N / BM, 8), 256, 0, stream>>>(x, sq, minkey);
    k_final<<<N / 256, 256, 0, stream>>>(x, minkey, d_ap, out);
}

// Round 2
// 95.973 us; speedup vs baseline: 3.3512x; 3.3512x over previous
//
#include <hip/hip_runtime.h>

#define N 8192
#define D 128
#define NC 512
#define CSZ 16

typedef __attribute__((ext_vector_type(8))) short bf16x8;
typedef __attribute__((ext_vector_type(4))) float f32x4;
typedef unsigned long long u64;

__device__ __forceinline__ unsigned short f2bf(float f) {
    unsigned u = __float_as_uint(f);
    u += 0x7FFF + ((u >> 16) & 1);   // round-to-nearest-even
    return (unsigned short)(u >> 16);
}

// ---------------- kernel 1: sq norms + minkey init ----------------
__global__ void k_sq_init(const float* __restrict__ x, float* __restrict__ sq,
                          u64* __restrict__ minkey) {
    int i = blockIdx.x * blockDim.x + threadIdx.x;
    if (i >= N) return;
    const float4* xr = (const float4*)(x + (size_t)i * D);
    float s = 0.f;
#pragma unroll
    for (int k = 0; k < D / 4; ++k) {
        float4 v = xr[k];
        s += v.x * v.x + v.y * v.y + v.z * v.z + v.w * v.w;
    }
    sq[i] = s;
    minkey[i] = ~0ULL;
}

// ---------------- kernel 2: hardest positive (exact fp32, 16-elem cluster) --
__global__ __launch_bounds__(256) void k_pos(const float* __restrict__ x,
                                             float* __restrict__ d_ap) {
    __shared__ __align__(16) float Xs[CSZ][D + 4];
    __shared__ float dist[CSZ][CSZ + 1];
    int c = blockIdx.x;
    int tid = threadIdx.x;
#pragma unroll
    for (int it = 0; it < 2; ++it) {
        int idx = tid + it * 256;     // float4 index
        int r = idx >> 5, k4 = idx & 31;
        float4 v = *(const float4*)(x + (size_t)(c * CSZ + r) * D + k4 * 4);
        Xs[r][k4 * 4 + 0] = v.x;
        Xs[r][k4 * 4 + 1] = v.y;
        Xs[r][k4 * 4 + 2] = v.z;
        Xs[r][k4 * 4 + 3] = v.w;
    }
    __syncthreads();
    int r = tid >> 4, cc = tid & 15;
    float s = 0.f;
#pragma unroll 8
    for (int k = 0; k < D; ++k) {
        float d = Xs[r][k] - Xs[cc][k];
        s += d * d;
    }
    dist[r][cc] = sqrtf(s);
    __syncthreads();
    if (tid < CSZ) {
        float best = -1.f;
#pragma unroll
        for (int j = 0; j < CSZ; ++j) {
            float v = dist[tid][j];
            if (v > best) best = v;
        }
        d_ap[c * CSZ + tid] = best;
    }
}

// ---------------- kernel 3: hardest negative via bf16 MFMA gram tiles -------
// 128x128 tile per block, 4 waves each 64x64 (4x4 frags of 16x16x32 MFMA).
__global__ __launch_bounds__(256, 2) void k_neg(const float* __restrict__ x,
                                                const float* __restrict__ sq,
                                                u64* __restrict__ minkey) {
    __shared__ __align__(16) unsigned short At[128 * 128];  // 32 KB, swizzled
    __shared__ __align__(16) unsigned short Bt[128 * 128];  // 32 KB, swizzled

    const int row0 = blockIdx.x * 128, col0 = blockIdx.y * 128;
    const int tid = threadIdx.x;

    // stage + fp32->bf16 convert; 2048 16B chunks per tile, 8 per thread.
    // chunk (r,c) stored at byte r*256 + ((c*16) ^ ((r&7)<<4))  [T2 swizzle]
    for (int half = 0; half < 2; ++half) {
        unsigned short* dst = half ? Bt : At;
        const int base = half ? col0 : row0;
#pragma unroll
        for (int it = 0; it < 8; ++it) {
            int idx = tid + it * 256;
            int r = idx >> 4, c = idx & 15;
            const float4* src = (const float4*)(x + (size_t)(base + r) * D + c * 8);
            float4 v0 = src[0], v1 = src[1];
            union { unsigned short s[8]; uint4 v; } o;
            o.s[0] = f2bf(v0.x); o.s[1] = f2bf(v0.y);
            o.s[2] = f2bf(v0.z); o.s[3] = f2bf(v0.w);
            o.s[4] = f2bf(v1.x); o.s[5] = f2bf(v1.y);
            o.s[6] = f2bf(v1.z); o.s[7] = f2bf(v1.w);
            *(uint4*)((char*)dst + r * 256 + ((c * 16) ^ ((r & 7) << 4))) = o.v;
        }
    }
    __syncthreads();

    const int lane = tid & 63;
    const int wave = tid >> 6;
    const int wrow = (wave >> 1) * 64, wcol = (wave & 1) * 64;
    const int lr = lane & 15, lg = lane >> 4;

    f32x4 acc[4][4] = {};   // [fi][fj]
#pragma unroll
    for (int kk = 0; kk < 4; ++kk) {          // K-step of 32
        const int kb = kk * 64 + lg * 16;     // per-lane k byte offset
        bf16x8 af[4], bfr[4];
#pragma unroll
        for (int f = 0; f < 4; ++f) {
            int ra = wrow + f * 16 + lr;
            af[f] = *(const bf16x8*)((const char*)At + ra * 256 + (kb ^ ((ra & 7) << 4)));
            int rb = wcol + f * 16 + lr;
            bfr[f] = *(const bf16x8*)((const char*)Bt + rb * 256 + (kb ^ ((rb & 7) << 4)));
        }
#pragma unroll
        for (int fi = 0; fi < 4; ++fi)
#pragma unroll
            for (int fj = 0; fj < 4; ++fj)
                acc[fi][fj] = __builtin_amdgcn_mfma_f32_16x16x32_bf16(
                    af[fi], bfr[fj], acc[fi][fj], 0, 0, 0);
    }

    __syncthreads();              // all tile reads done -> reuse At for reduce
    u64* red = (u64*)At;          // [128][2]

    float sqj[4];
#pragma unroll
    for (int fj = 0; fj < 4; ++fj) sqj[fj] = sq[col0 + wcol + fj * 16 + lr];

#pragma unroll
    for (int fi = 0; fi < 4; ++fi) {
#pragma unroll
        for (int j = 0; j < 4; ++j) {
            const int li = wrow + fi * 16 + lg * 4 + j;   // C-row within tile
            const int gi = row0 + li;
            const float si = sq[gi];
            u64 best = ~0ULL;
#pragma unroll
            for (int fj = 0; fj < 4; ++fj) {
                const int gj = col0 + wcol + fj * 16 + lr;
                float d2 = fmaxf(si + sqj[fj] - 2.0f * acc[fi][fj][j], 0.0f);
                u64 key = ((u64)__float_as_uint(d2) << 32) | (unsigned)gj;
                if (((gi >> 4) != (gj >> 4)) && key < best) best = key;
            }
#pragma unroll
            for (int m = 1; m < 16; m <<= 1) {
                u64 o = __shfl_xor(best, m);
                if (o < best) best = o;
            }
            if (lr == 0) red[li * 2 + (wave & 1)] = best;
        }
    }
    __syncthreads();
    if (tid < 128) {
        u64 a = red[tid * 2], b = red[tid * 2 + 1];
        atomicMin(&minkey[row0 + tid], a < b ? a : b);
    }
}

// ---------------- kernel 4: exact d_an + triplet loss ----------------
__global__ void k_final(const float* __restrict__ x,
                        const u64* __restrict__ minkey,
                        const float* __restrict__ d_ap, float* __restrict__ out) {
    int i = blockIdx.x * blockDim.x + threadIdx.x;
    if (i >= N) return;
    int j = (int)(minkey[i] & 0xFFFFFFFFULL);
    const float4* xi = (const float4*)(x + (size_t)i * D);
    const float4* xj = (const float4*)(x + (size_t)j * D);
    float s = 0.f;
#pragma unroll
    for (int k = 0; k < D / 4; ++k) {
        float4 a = xi[k], b = xj[k];
        float dx = a.x - b.x, dy = a.y - b.y, dz = a.z - b.z, dw = a.w - b.w;
        s += dx * dx + dy * dy + dz * dz + dw * dw;
    }
    float d_an = sqrtf(s);
    out[i] = fmaxf(d_ap[i] - d_an + 1.0f, 0.0f);
}

extern "C" void kernel_launch(void* const* d_in, const int* in_sizes, int n_in,
                              void* d_out, int out_size, void* d_ws, size_t ws_size,
                              hipStream_t stream) {
    const float* x = (const float*)d_in[0];
    float* out = (float*)d_out;

    char* ws = (char*)d_ws;
    float* sq = (float*)ws;                                   // 32 KB
    u64* minkey = (u64*)(ws + 32768);                         // 64 KB
    float* d_ap = (float*)(ws + 98304);                       // 32 KB

    k_sq_init<<<N / 256, 256, 0, stream>>>(x, sq, minkey);
    k_pos<<<NC, 256, 0, stream>>>(x, d_ap);
    k_neg<<<dim3(N / 128, N / 128), 256, 0, stream>>>(x, sq, minkey);
    k_final<<<N / 256, 256, 0, stream>>>(x, minkey, d_ap, out);
}

// Round 3
// 84.307 us; speedup vs baseline: 3.8148x; 1.1384x over previous
//
#include <hip/hip_runtime.h>

#define N 8192
#define D 128
#define NT 64                    // 128-row tiles
#define NBLK (NT * (NT + 1) / 2) // 2080 upper-triangular tile pairs

typedef __attribute__((ext_vector_type(8))) short bf16x8;
typedef __attribute__((ext_vector_type(4))) float f32x4;

__device__ __forceinline__ unsigned short f2bf(float f) {
    unsigned u = __float_as_uint(f);
    u += 0x7FFF + ((u >> 16) & 1);   // round-to-nearest-even
    return (unsigned short)(u >> 16);
}

// ---------------- kernel 1: sq norms + minkey init ----------------
__global__ void k_prep(const float* __restrict__ x, float* __restrict__ sq,
                       unsigned* __restrict__ minkey) {
    int i = blockIdx.x * blockDim.x + threadIdx.x;
    if (i >= N) return;
    const float4* xr = (const float4*)(x + (size_t)i * D);
    float s = 0.f;
#pragma unroll
    for (int k = 0; k < D / 4; ++k) {
        float4 v = xr[k];
        s += v.x * v.x + v.y * v.y + v.z * v.z + v.w * v.w;
    }
    sq[i] = s;
    minkey[i] = 0xFFFFFFFFu;
}

// stage one 128x128 fp32 tile as bf16 into swizzled LDS
__device__ __forceinline__ void stage_tile(unsigned short* dst,
                                           const float* __restrict__ srcbase,
                                           int tid) {
#pragma unroll
    for (int it = 0; it < 8; ++it) {
        int idx = tid + it * 256;
        int r = idx >> 4, c = idx & 15;
        const float4* src = (const float4*)(srcbase + (size_t)r * D + c * 8);
        float4 v0 = src[0], v1 = src[1];
        union { unsigned short s[8]; uint4 v; } o;
        o.s[0] = f2bf(v0.x); o.s[1] = f2bf(v0.y);
        o.s[2] = f2bf(v0.z); o.s[3] = f2bf(v0.w);
        o.s[4] = f2bf(v1.x); o.s[5] = f2bf(v1.y);
        o.s[6] = f2bf(v1.z); o.s[7] = f2bf(v1.w);
        *(uint4*)((char*)dst + r * 256 + ((c * 16) ^ ((r & 7) << 4))) = o.v;
    }
}

// ---------------- kernel 2: symmetric tiled gram + min/max fold -------------
// Upper-triangular 128x128 tiles. Off-diag: fold row-mins AND col-mins.
// Diag: same-cluster <=> fragment fi==fj on waves with wrow==wcol -> d_ap.
__global__ __launch_bounds__(256, 2) void k_neg(const float* __restrict__ x,
                                                const float* __restrict__ sq,
                                                unsigned* __restrict__ minkey,
                                                float* __restrict__ d_ap2) {
    __shared__ __align__(16) unsigned short At[128 * 128];  // 32 KB
    __shared__ __align__(16) unsigned short Bt[128 * 128];  // 32 KB

    // triangular decode: bi <= bj
    int b = blockIdx.x;
    int bi = 0;
    while (b >= NT - bi) { b -= NT - bi; ++bi; }
    const int bj = bi + b;
    const int row0 = bi * 128, col0 = bj * 128;
    const bool isdiag = (bi == bj);

    const int tid = threadIdx.x;
    stage_tile(At, x + (size_t)row0 * D, tid);
    if (!isdiag) stage_tile(Bt, x + (size_t)col0 * D, tid);
    __syncthreads();
    const unsigned short* Bp = isdiag ? At : Bt;

    const int lane = tid & 63;
    const int wave = tid >> 6;
    const int wrow = (wave >> 1) * 64, wcol = (wave & 1) * 64;
    const int lr = lane & 15, lg = lane >> 4;

    f32x4 acc[4][4] = {};   // [fi][fj]
#pragma unroll
    for (int kk = 0; kk < 4; ++kk) {          // K-step of 32
        const int kb = kk * 64 + lg * 16;     // per-lane k byte offset
        bf16x8 af[4], bfr[4];
#pragma unroll
        for (int f = 0; f < 4; ++f) {
            int ra = wrow + f * 16 + lr;
            af[f] = *(const bf16x8*)((const char*)At + ra * 256 + (kb ^ ((ra & 7) << 4)));
            int rb = wcol + f * 16 + lr;
            bfr[f] = *(const bf16x8*)((const char*)Bp + rb * 256 + (kb ^ ((rb & 7) << 4)));
        }
#pragma unroll
        for (int fi = 0; fi < 4; ++fi)
#pragma unroll
            for (int fj = 0; fj < 4; ++fj)
                acc[fi][fj] = __builtin_amdgcn_mfma_f32_16x16x32_bf16(
                    af[fi], bfr[fj], acc[fi][fj], 0, 0, 0);
    }

    // ---------------- epilogue: f32 min/max folds, u32 atomics ----------------
    const bool diagwave = isdiag && (wrow == wcol);
    const float INF = __int_as_float(0x7F800000);

    float sjv[4];
#pragma unroll
    for (int fj = 0; fj < 4; ++fj) sjv[fj] = sq[col0 + wcol + fj * 16 + lr];

    float colmin[4] = {INF, INF, INF, INF};

#pragma unroll
    for (int fi = 0; fi < 4; ++fi) {
#pragma unroll
        for (int j = 0; j < 4; ++j) {
            const int gi = row0 + wrow + fi * 16 + lg * 4 + j;
            const float si = sq[gi];
            float rmin = INF, rmax = -INF;
#pragma unroll
            for (int fj = 0; fj < 4; ++fj) {
                const float dot = acc[fi][fj][j];
                const float r2 = fmaf(-2.f, dot, sjv[fj]);   // sj - 2*dot
                if (diagwave && fj == fi) {
                    rmax = fmaxf(rmax, r2);                   // same-cluster: pos
                } else {
                    rmin = fminf(rmin, r2);                   // cross-cluster: neg
                    if (!isdiag)
                        colmin[fj] = fminf(colmin[fj], fmaf(-2.f, dot, si));
                }
            }
#pragma unroll
            for (int m = 1; m < 16; m <<= 1)
                rmin = fminf(rmin, __shfl_xor(rmin, m));
            if (diagwave) {
#pragma unroll
                for (int m = 1; m < 16; m <<= 1)
                    rmax = fmaxf(rmax, __shfl_xor(rmax, m));
                if (lr == 0) d_ap2[gi] = fmaxf(si + rmax, 0.f);
            }
            if (lr == 0)
                atomicMin(&minkey[gi], __float_as_uint(fmaxf(si + rmin, 0.f)));
        }
    }

    if (!isdiag) {
#pragma unroll
        for (int fj = 0; fj < 4; ++fj) {
            float cm = colmin[fj];
            cm = fminf(cm, __shfl_xor(cm, 16));
            cm = fminf(cm, __shfl_xor(cm, 32));
            if (lg == 0)
                atomicMin(&minkey[col0 + wcol + fj * 16 + lr],
                          __float_as_uint(fmaxf(sjv[fj] + cm, 0.f)));
        }
    }
}

// ---------------- kernel 3: final loss ----------------
__global__ void k_final(const unsigned* __restrict__ minkey,
                        const float* __restrict__ d_ap2, float* __restrict__ out) {
    int i = blockIdx.x * blockDim.x + threadIdx.x;
    if (i >= N) return;
    float d_an = sqrtf(__uint_as_float(minkey[i]));
    float d_ap = sqrtf(d_ap2[i]);
    out[i] = fmaxf(d_ap - d_an + 1.0f, 0.0f);
}

extern "C" void kernel_launch(void* const* d_in, const int* in_sizes, int n_in,
                              void* d_out, int out_size, void* d_ws, size_t ws_size,
                              hipStream_t stream) {
    const float* x = (const float*)d_in[0];
    float* out = (float*)d_out;

    char* ws = (char*)d_ws;
    float* sq = (float*)ws;                          // 32 KB
    unsigned* minkey = (unsigned*)(ws + 32768);      // 32 KB
    float* d_ap2 = (float*)(ws + 65536);             // 32 KB

    k_prep<<<N / 256, 256, 0, stream>>>(x, sq, minkey);
    k_neg<<<NBLK, 256, 0, stream>>>(x, sq, minkey, d_ap2);
    k_final<<<N / 256, 256, 0, stream>>>(minkey, d_ap2, out);
}

// Round 4
// 37.394 us; speedup vs baseline: 8.6008x; 2.2546x over previous
//
#include <hip/hip_runtime.h>

#define N 8192
#define D 128
#define NC 512
#define NCT 8                  // col-tiles (of 128) per block: 1024 cols

typedef __attribute__((ext_vector_type(8))) short bf16x8;
typedef __attribute__((ext_vector_type(4))) float f32x4;
typedef unsigned int u32;
typedef unsigned short u16;

__device__ __forceinline__ u16 f2bf(float f) {
    u32 u = __float_as_uint(f);
    u += 0x7FFF + ((u >> 16) & 1);   // round-to-nearest-even
    return (u16)(u >> 16);
}

// async global->LDS, 16B/lane; dst base must be wave-uniform (HW adds lane*16)
__device__ __forceinline__ void gl_lds16(const u16* g, u16* l) {
    __builtin_amdgcn_global_load_lds(
        (const __attribute__((address_space(1))) u32*)g,
        (__attribute__((address_space(3))) u32*)l, 16, 0, 0);
}

// ---- kernel 1: exact d_ap per cluster + bf16 copy + sq + minkey init -------
__global__ __launch_bounds__(256) void k_prep(const float* __restrict__ x,
                                              u16* __restrict__ xbf,
                                              float* __restrict__ sq,
                                              u32* __restrict__ minkey,
                                              float* __restrict__ d_ap) {
    __shared__ __align__(16) float Xs[16][D + 4];
    __shared__ float dist[16][17];
    const int cl = blockIdx.x, tid = threadIdx.x;
#pragma unroll
    for (int it = 0; it < 2; ++it) {
        int idx = tid + it * 256;
        int r = idx >> 5, k4 = idx & 31;
        float4 v = *(const float4*)(x + (size_t)(cl * 16 + r) * D + k4 * 4);
        Xs[r][k4 * 4 + 0] = v.x;
        Xs[r][k4 * 4 + 1] = v.y;
        Xs[r][k4 * 4 + 2] = v.z;
        Xs[r][k4 * 4 + 3] = v.w;
    }
    __syncthreads();
    const int r = tid >> 4, cc = tid & 15;
    float s = 0.f;
#pragma unroll 8
    for (int k = 0; k < D; ++k) {
        float d = Xs[r][k] - Xs[cc][k];
        s += d * d;
    }
    dist[r][cc] = sqrtf(s);
    // bf16 copy: thread (r,cc) converts chunk cc (8 elems) of row r
    union { u16 h[8]; uint4 v; } o;
#pragma unroll
    for (int e = 0; e < 8; ++e) o.h[e] = f2bf(Xs[r][cc * 8 + e]);
    *(uint4*)(xbf + (size_t)(cl * 16 + r) * D + cc * 8) = o.v;
    __syncthreads();
    if (tid < 16) {
        float best = -1.f, ss = 0.f;
#pragma unroll
        for (int j = 0; j < 16; ++j) best = fmaxf(best, dist[tid][j]);
#pragma unroll 8
        for (int k = 0; k < D; ++k) ss += Xs[tid][k] * Xs[tid][k];
        d_ap[cl * 16 + tid] = best;
        sq[cl * 16 + tid] = ss;
        minkey[cl * 16 + tid] = 0xFFFFFFFFu;
    }
}

// ---- kernel 2: hardest negative, panel-resident A, pipelined B -------------
// grid (32,8): block = rows [bi*256,+256) x cols [cg*1024,+1024)
// LDS: A 64KB resident + B 2x32KB double-buffer = 128KB -> 1 block/CU, 8 waves
__global__ __launch_bounds__(512, 2) void k_neg(const u16* __restrict__ xbf,
                                                const float* __restrict__ sq,
                                                u32* __restrict__ minkey) {
    __shared__ __align__(16) u16 Al[256 * 128];       // 64 KB
    __shared__ __align__(16) u16 Bl[2][128 * 128];    // 2 x 32 KB

    const int row0 = blockIdx.x * 256;
    const int col00 = blockIdx.y * 1024;
    const int tid = threadIdx.x;
    const int lane = tid & 63, wave = tid >> 6;
    const int lr = lane & 15, lg = lane >> 4;
    const int wr = wave >> 1, wc = wave & 1;          // 4x2 wave grid, 64x64 each

    // prologue: stage A (8 issues/wave) + B tile 0 (4 issues/wave).
    // LDS linear; swizzle via per-lane global chunk (lr ^ (row&7))  [m173]
#pragma unroll
    for (int it = 0; it < 8; ++it) {
        const int ra0 = wave * 32 + it * 4;
        const int r = ra0 + (lane >> 4);
        gl_lds16(xbf + (size_t)(row0 + r) * D + ((lr ^ (r & 7)) * 8),
                 Al + ra0 * 128);
    }
#pragma unroll
    for (int it = 0; it < 4; ++it) {
        const int rb0 = wave * 16 + it * 4;
        const int r = rb0 + (lane >> 4);
        gl_lds16(xbf + (size_t)(col00 + r) * D + ((lr ^ (r & 7)) * 8),
                 Bl[0] + rb0 * 128);
    }
    __syncthreads();   // drains vmcnt(0): A + B0 resident

    const float INF = __int_as_float(0x7F800000);
    float rmin[4][4] = {{INF, INF, INF, INF}, {INF, INF, INF, INF},
                        {INF, INF, INF, INF}, {INF, INF, INF, INF}};
    int cur = 0;

    for (int t = 0; t < NCT; ++t) {
        // prefetch next B tile into the other buffer (issue before compute)
        if (t + 1 < NCT) {
            const int c0n = col00 + (t + 1) * 128;
#pragma unroll
            for (int it = 0; it < 4; ++it) {
                const int rb0 = wave * 16 + it * 4;
                const int r = rb0 + (lane >> 4);
                gl_lds16(xbf + (size_t)(c0n + r) * D + ((lr ^ (r & 7)) * 8),
                         Bl[cur ^ 1] + rb0 * 128);
            }
        }

        const u16* Bp = Bl[cur];
        f32x4 acc[4][4] = {};
#pragma unroll
        for (int kk = 0; kk < 4; ++kk) {
            const int kx = (kk * 64 + lg * 16) ^ ((lr & 7) << 4);
            bf16x8 af[4], bfv[4];
#pragma unroll
            for (int f = 0; f < 4; ++f) {
                af[f]  = *(const bf16x8*)((const char*)Al + (wr * 64 + f * 16 + lr) * 256 + kx);
                bfv[f] = *(const bf16x8*)((const char*)Bp + (wc * 64 + f * 16 + lr) * 256 + kx);
            }
#pragma unroll
            for (int fi = 0; fi < 4; ++fi)
#pragma unroll
                for (int fj = 0; fj < 4; ++fj)
                    acc[fi][fj] = __builtin_amdgcn_mfma_f32_16x16x32_bf16(
                        af[fi], bfv[fj], acc[fi][fj], 0, 0, 0);
        }

        // fold this tile into register-resident row minima
        const int c0 = col00 + t * 128;
        float sjv[4];
#pragma unroll
        for (int fj = 0; fj < 4; ++fj) sjv[fj] = sq[c0 + wc * 64 + fj * 16 + lr];

        if (c0 >= row0 && c0 < row0 + 256) {   // tile overlaps own rows: mask
#pragma unroll
            for (int fi = 0; fi < 4; ++fi)
#pragma unroll
                for (int jj = 0; jj < 4; ++jj) {
                    const int gi = row0 + wr * 64 + fi * 16 + lg * 4 + jj;
#pragma unroll
                    for (int fj = 0; fj < 4; ++fj) {
                        const int gj = c0 + wc * 64 + fj * 16 + lr;
                        float r2 = fmaf(-2.f, acc[fi][fj][jj], sjv[fj]);
                        if ((gi >> 4) == (gj >> 4)) r2 = INF;
                        rmin[fi][jj] = fminf(rmin[fi][jj], r2);
                    }
                }
        } else {
#pragma unroll
            for (int fi = 0; fi < 4; ++fi)
#pragma unroll
                for (int jj = 0; jj < 4; ++jj)
#pragma unroll
                    for (int fj = 0; fj < 4; ++fj)
                        rmin[fi][jj] = fminf(rmin[fi][jj],
                                             fmaf(-2.f, acc[fi][fj][jj], sjv[fj]));
        }

        __syncthreads();   // drains vmcnt (next tile staged) + read fence
        cur ^= 1;
    }

    // once-per-block reduction + atomic
#pragma unroll
    for (int fi = 0; fi < 4; ++fi)
#pragma unroll
        for (int jj = 0; jj < 4; ++jj) {
            float v = rmin[fi][jj];
            v = fminf(v, __shfl_xor(v, 1));
            v = fminf(v, __shfl_xor(v, 2));
            v = fminf(v, __shfl_xor(v, 4));
            v = fminf(v, __shfl_xor(v, 8));
            if (lr == 0) {
                const int gi = row0 + wr * 64 + fi * 16 + lg * 4 + jj;
                const float d2 = fmaxf(sq[gi] + v, 0.f);
                atomicMin(&minkey[gi], __float_as_uint(d2));
            }
        }
}

// ---- kernel 3: final loss ----
__global__ void k_final(const u32* __restrict__ minkey,
                        const float* __restrict__ d_ap, float* __restrict__ out) {
    int i = blockIdx.x * blockDim.x + threadIdx.x;
    if (i >= N) return;
    float d_an = sqrtf(__uint_as_float(minkey[i]));
    out[i] = fmaxf(d_ap[i] - d_an + 1.0f, 0.0f);
}

extern "C" void kernel_launch(void* const* d_in, const int* in_sizes, int n_in,
                              void* d_out, int out_size, void* d_ws, size_t ws_size,
                              hipStream_t stream) {
    const float* x = (const float*)d_in[0];
    float* out = (float*)d_out;

    char* ws = (char*)d_ws;
    u16* xbf = (u16*)ws;                              // 2 MB bf16 copy
    float* sq = (float*)(ws + 2097152);               // 32 KB
    u32* minkey = (u32*)(ws + 2097152 + 32768);       // 32 KB
    float* d_ap = (float*)(ws + 2097152 + 65536);     // 32 KB

    k_prep<<<NC, 256, 0, stream>>>(x, xbf, sq, minkey, d_ap);
    k_neg<<<dim3(32, 8), 512, 0, stream>>>(xbf, sq, minkey);
    k_final<<<N / 256, 256, 0, stream>>>(minkey, d_ap, out);
}